// Round 5
// baseline (605.442 us; speedup 1.0000x reference)
//
#include <hip/hip_runtime.h>
#include <hip/hip_fp16.h>
#include <math.h>

// ---------------------------------------------------------------------------
// DeepECCNet: 3-layer gated graph conv + t-gate + MLP head.
// v15: agg x8 in-flight gathers. v16: padded atomic counters (NEUTRAL: rank
//      is fabric-atomic-throughput bound, not line-contention bound).
// v17: agg VALU diet. Per-layer CSR records uint2{src*256, gate_f32_bits}:
//      - gate decode (bfe+cvt+mul) -> free bit reinterpret
//      - row address -> one 32-bit add, saddr-form load off uniform ht base
//      per-edge VALU ~9-10 -> ~5 (VALUBusy was 57% = co-limiter).
//      scatter writes 3 arrays (+25.6MB, ~+4us). counts aliases csr0,
//      slot aliases h16 head. Predict agg 66.2 -> ~53us, total ~510.
// ---------------------------------------------------------------------------

typedef _Float16 f16x8 __attribute__((ext_vector_type(8)));
typedef float f32x4 __attribute__((ext_vector_type(4)));

#define CNT_STRIDE 32  // one counter per 128B line (kept from v16; harmless)

__device__ __forceinline__ float sigmoidf_(float v) { return 1.f / (1.f + expf(-v)); }

__global__ void sentinel_kernel(float* __restrict__ out, int n, float val) {
  int i = blockIdx.x * 256 + threadIdx.x;
  if (i < n) out[i] = val;
}

// ---- init: zero strided counts + detect int64 edge_index -------------------
__global__ void init_kernel(const int* __restrict__ ei, int* __restrict__ flag,
                            int* __restrict__ counts, int n) {
  int i = blockIdx.x * 256 + threadIdx.x;
  if (i < n * CNT_STRIDE) counts[i] = 0;
  if (i == 0) {
    int all0 = 1;
    for (int k = 1; k < 512; k += 2) {
      if (ei[k] != 0) { all0 = 0; break; }
    }
    *flag = all0;
  }
}

// ---- rank: slot[e] = within-target rank via counting atomic ----------------
__global__ void rank_kernel(const int* __restrict__ ei, int E, int n,
                            const int* __restrict__ flag,
                            int* __restrict__ slot, int* __restrict__ counts) {
  int e = blockIdx.x * blockDim.x + threadIdx.x;
  if (e >= E) return;
  int t;
  if (*flag) {
    t = (int)((const long long*)ei)[(size_t)E + e];
  } else {
    t = ei[(size_t)E + e];
  }
  slot[e] = ((unsigned)t < (unsigned)n) ? atomicAdd(&counts[(size_t)t * CNT_STRIDE], 1) : -1;
}

__global__ void scan1_kernel(const int* __restrict__ counts, int n,
                             int* __restrict__ starts, int* __restrict__ bsums) {
  __shared__ int tmp[256];
  int i = blockIdx.x * 256 + threadIdx.x;
  int v = (i < n) ? counts[(size_t)i * CNT_STRIDE] : 0;
  tmp[threadIdx.x] = v;
  __syncthreads();
  for (int off = 1; off < 256; off <<= 1) {
    int t = (threadIdx.x >= (unsigned)off) ? tmp[threadIdx.x - off] : 0;
    __syncthreads();
    tmp[threadIdx.x] += t;
    __syncthreads();
  }
  if (i < n) starts[i] = tmp[threadIdx.x] - v;  // exclusive
  if (threadIdx.x == 255) bsums[blockIdx.x] = tmp[255];
}

__global__ void scan2_kernel(int* __restrict__ bsums, int nb, int* __restrict__ total) {
  __shared__ int tmp[512];
  int v = (threadIdx.x < (unsigned)nb) ? bsums[threadIdx.x] : 0;
  tmp[threadIdx.x] = v;
  __syncthreads();
  for (int off = 1; off < 512; off <<= 1) {
    int t = (threadIdx.x >= (unsigned)off) ? tmp[threadIdx.x - off] : 0;
    __syncthreads();
    tmp[threadIdx.x] += t;
    __syncthreads();
  }
  if (threadIdx.x < (unsigned)nb) bsums[threadIdx.x] = tmp[threadIdx.x] - v;  // exclusive
  if (threadIdx.x == 511) *total = tmp[511];  // grand total -> starts[n]
}

__global__ void scan3_kernel(int* __restrict__ starts, const int* __restrict__ bsums, int n) {
  int i = blockIdx.x * 256 + threadIdx.x;
  if (i < n) starts[i] += bsums[blockIdx.x];
}

// ---- scatter: csrL[pos] = {src*256, f32 gate_L bits} (8B x 3 layers) -------
__global__ void scatter_kernel(const int* __restrict__ ei, const int* __restrict__ slot,
                               const int* __restrict__ starts,
                               const float* __restrict__ ea, int E, int n,
                               const int* __restrict__ flag,
                               const float* __restrict__ w0p,
                               const float* __restrict__ w1p,
                               const float* __restrict__ w2p,
                               uint2* __restrict__ csr0,
                               uint2* __restrict__ csr1,
                               uint2* __restrict__ csr2) {
  float w0 = w0p[0], w1 = w1p[0], w2 = w2p[0];
  int f64 = *flag;
  const long long* e64 = (const long long*)ei;
  int base = blockIdx.x * blockDim.x + threadIdx.x;
  int stride = gridDim.x * blockDim.x;
#pragma unroll
  for (int u = 0; u < 4; u++) {
    int e = base + u * stride;
    if (e < E) {
      int sl = slot[e];
      if (sl >= 0) {
        int s, t;
        if (f64) {
          s = (int)e64[e];
          t = (int)e64[(size_t)E + e];
        } else {
          s = ei[e];
          t = ei[(size_t)E + e];
        }
        int pos = starts[t] + sl;
        if ((unsigned)pos < (unsigned)E) {
          float a = ea[e];
          unsigned boff = (unsigned)min(max(s, 0), n - 1) * 256u;  // byte offset of row
          csr0[pos] = make_uint2(boff, __float_as_uint(sigmoidf_(a * w0)));
          csr1[pos] = make_uint2(boff, __float_as_uint(sigmoidf_(a * w1)));
          csr2[pos] = make_uint2(boff, __float_as_uint(sigmoidf_(a * w2)));
        }
      }
    }
  }
}

// ---- h0 = fp16(x[:, 1:]); x0 = x[:, 0] -------------------------------------
__global__ void slice_kernel(const float* __restrict__ x, _Float16* __restrict__ h,
                             float* __restrict__ x0, int n) {
  int idx = blockIdx.x * blockDim.x + threadIdx.x;
  if (idx < n * 128) {
    int node = idx >> 7;
    int k = idx & 127;
    h[idx] = (_Float16)x[(size_t)node * 129 + 1 + k];
  }
  if (idx < n) x0[idx] = x[(size_t)idx * 129];
}

// ---- unified MFMA head: out = sigmoid( relu(h@W1[hrow0:hrow0+128] +
//        extra*W1[xrow] + b1) @ w2 + b2 )
__global__ __launch_bounds__(256) void head_mfma_kernel(const _Float16* __restrict__ h,
    const float* __restrict__ extra, const float* __restrict__ W1,
    const float* __restrict__ b1, const float* __restrict__ w2,
    const float* __restrict__ b2, float* __restrict__ out, int n,
    int hrow0, int xrow) {
  __shared__ __align__(16) _Float16 sB[4 * 4 * 64 * 8];  // 16 KB, B-frag order
  __shared__ float sWx[64], sB1[64], sW2[64];
  for (int idx = threadIdx.x; idx < 8192; idx += 256) {
    int k = idx >> 6, col = idx & 63;
    float w = W1[(size_t)(hrow0 + k) * 64 + col];
    int ks = k >> 5, quad = (k >> 3) & 3, j = k & 7;
    int nt = col >> 4, cl = col & 15;
    sB[(((ks * 4 + nt) * 64) + quad * 16 + cl) * 8 + j] = (_Float16)w;
  }
  if (threadIdx.x < 64) {
    sWx[threadIdx.x] = W1[(size_t)xrow * 64 + threadIdx.x];
    sB1[threadIdx.x] = b1[threadIdx.x];
    sW2[threadIdx.x] = w2[threadIdx.x];
  }
  __syncthreads();
  int wv = threadIdx.x >> 6, lane = threadIdx.x & 63;
  int quad = lane >> 4, l15 = lane & 15;
  int n0 = (blockIdx.x * 4 + wv) * 16;
  if (n0 >= n) return;
  int node_a = min(n0 + l15, n - 1);
  const _Float16* hrow = h + (size_t)node_a * 128 + quad * 8;

  f32x4 acc[4];
#pragma unroll
  for (int t = 0; t < 4; t++) acc[t] = (f32x4){0.f, 0.f, 0.f, 0.f};
  for (int ks = 0; ks < 4; ks++) {
    f16x8 afrag = *(const f16x8*)(hrow + ks * 32);
    const f16x8* bp = (const f16x8*)sB;
#pragma unroll
    for (int t = 0; t < 4; t++) {
      f16x8 bfrag = bp[(ks * 4 + t) * 64 + lane];
      acc[t] = __builtin_amdgcn_mfma_f32_16x16x32_f16(afrag, bfrag, acc[t], 0, 0, 0);
    }
  }
  float b2v = b2[0];
  float xv[4], part[4] = {0.f, 0.f, 0.f, 0.f};
#pragma unroll
  for (int r = 0; r < 4; r++) xv[r] = extra[min(n0 + quad * 4 + r, n - 1)];
#pragma unroll
  for (int t = 0; t < 4; t++) {
    int col = t * 16 + l15;
    float wx = sWx[col], bb = sB1[col], w2v = sW2[col];
#pragma unroll
    for (int r = 0; r < 4; r++) {
      float u = fmaxf(acc[t][r] + xv[r] * wx + bb, 0.f);
      part[r] += u * w2v;
    }
  }
#pragma unroll
  for (int r = 0; r < 4; r++) {
    float p = part[r];
    p += __shfl_xor(p, 1); p += __shfl_xor(p, 2);
    p += __shfl_xor(p, 4); p += __shfl_xor(p, 8);
    int node = n0 + quad * 4 + r;
    if (l15 == 0 && node < n) out[node] = sigmoidf_(p + b2v);
  }
}

// ---- MFMA GEMM: ht16 = f16(h16 @ W + b); grid-stride over 64-node tiles ----
__global__ __launch_bounds__(256) void gemm_mfma_kernel(const _Float16* __restrict__ h,
    const float* __restrict__ Wg, const float* __restrict__ b,
    _Float16* __restrict__ out16, int n) {
  __shared__ __align__(16) _Float16 sB[4 * 8 * 64 * 8];  // 32 KB
  for (int i = threadIdx.x; i < 4096; i += 256) {  // i = float4 index over W
    int k = i >> 5;
    int n4 = (i & 31) * 4;
    float4 w4 = ((const float4*)Wg)[i];
    int ks = k >> 5, quad = (k >> 3) & 3, j = k & 7;
#pragma unroll
    for (int c = 0; c < 4; c++) {
      int col = n4 + c;
      int nt = col >> 4, cl = col & 15;
      sB[(((ks * 8 + nt) * 64) + quad * 16 + cl) * 8 + j] =
          (_Float16)((const float*)&w4)[c];
    }
  }
  __syncthreads();
  int wv = threadIdx.x >> 6, lane = threadIdx.x & 63;
  int quad = lane >> 4, l15 = lane & 15;
  int tiles = (n + 63) >> 6;
  for (int tile = blockIdx.x; tile < tiles; tile += gridDim.x) {
    int n0 = (tile * 4 + wv) * 16;
    if (n0 >= n) continue;
    int node_a = min(n0 + l15, n - 1);
    const _Float16* hrow = h + (size_t)node_a * 128 + quad * 8;

    f32x4 acc[8];
#pragma unroll
    for (int t = 0; t < 8; t++) acc[t] = (f32x4){0.f, 0.f, 0.f, 0.f};

    for (int ks = 0; ks < 4; ks++) {
      f16x8 afrag = *(const f16x8*)(hrow + ks * 32);
      const f16x8* bp = (const f16x8*)(sB + ks * 8 * 64 * 8);
#pragma unroll
      for (int t = 0; t < 8; t++) {
        f16x8 bfrag = bp[t * 64 + lane];
        acc[t] = __builtin_amdgcn_mfma_f32_16x16x32_f16(afrag, bfrag, acc[t], 0, 0, 0);
      }
    }
#pragma unroll
    for (int t = 0; t < 8; t++) {
      float bias = b[t * 16 + l15];
#pragma unroll
      for (int r = 0; r < 4; r++) {
        int node = n0 + quad * 4 + r;
        if (node < n)
          out16[(size_t)node * 128 + t * 16 + l15] = (_Float16)(acc[t][r] + bias);
      }
    }
  }
}

// ---- aggregation: fp16 rows, per-layer 8B records {byteoff, gate_f32} ------
// h' = f16( relu( (gs*ht[v] + sum_e g_e*ht[src_e]) / (deg+1) ) )
// deg = starts[node+1] - starts[node].
__global__ __launch_bounds__(256) void agg_kernel(const __half2* __restrict__ ht,
    const uint2* __restrict__ csr, const int* __restrict__ starts,
    const float* __restrict__ wp, __half2* __restrict__ hout, int n) {
  int wv = threadIdx.x >> 6, lane = threadIdx.x & 63;
  int node = blockIdx.x * 4 + wv;
  if (node >= n) return;
  int s = starts[node], c = starts[node + 1] - s;
  float gs = sigmoidf_(wp[0]);
  const char* htb = (const char*)ht;
  unsigned lane4 = (unsigned)lane * 4u;
  float2 v0 = __half22float2(*(const __half2*)(htb + ((unsigned)node * 256u + lane4)));
  float ax = gs * v0.x, ay = gs * v0.y;
  float bx = 0.f, by = 0.f;
  int j = 0;
  for (; j + 8 <= c; j += 8) {
    uint2 r0 = csr[s + j],     r1 = csr[s + j + 1];
    uint2 r2 = csr[s + j + 2], r3 = csr[s + j + 3];
    uint2 r4 = csr[s + j + 4], r5 = csr[s + j + 5];
    uint2 r6 = csr[s + j + 6], r7 = csr[s + j + 7];
    __half2 h0 = *(const __half2*)(htb + (r0.x + lane4));
    __half2 h1 = *(const __half2*)(htb + (r1.x + lane4));
    __half2 h2 = *(const __half2*)(htb + (r2.x + lane4));
    __half2 h3 = *(const __half2*)(htb + (r3.x + lane4));
    __half2 h4 = *(const __half2*)(htb + (r4.x + lane4));
    __half2 h5 = *(const __half2*)(htb + (r5.x + lane4));
    __half2 h6 = *(const __half2*)(htb + (r6.x + lane4));
    __half2 h7 = *(const __half2*)(htb + (r7.x + lane4));
    float g0 = __uint_as_float(r0.y), g1 = __uint_as_float(r1.y);
    float g2 = __uint_as_float(r2.y), g3 = __uint_as_float(r3.y);
    float g4 = __uint_as_float(r4.y), g5 = __uint_as_float(r5.y);
    float g6 = __uint_as_float(r6.y), g7 = __uint_as_float(r7.y);
    float2 f0 = __half22float2(h0), f1 = __half22float2(h1);
    float2 f2 = __half22float2(h2), f3 = __half22float2(h3);
    float2 f4 = __half22float2(h4), f5 = __half22float2(h5);
    float2 f6 = __half22float2(h6), f7 = __half22float2(h7);
    ax += g0 * f0.x; ay += g0 * f0.y;
    bx += g1 * f1.x; by += g1 * f1.y;
    ax += g2 * f2.x; ay += g2 * f2.y;
    bx += g3 * f3.x; by += g3 * f3.y;
    ax += g4 * f4.x; ay += g4 * f4.y;
    bx += g5 * f5.x; by += g5 * f5.y;
    ax += g6 * f6.x; ay += g6 * f6.y;
    bx += g7 * f7.x; by += g7 * f7.y;
  }
  for (; j + 4 <= c; j += 4) {
    uint2 r0 = csr[s + j],     r1 = csr[s + j + 1];
    uint2 r2 = csr[s + j + 2], r3 = csr[s + j + 3];
    __half2 h0 = *(const __half2*)(htb + (r0.x + lane4));
    __half2 h1 = *(const __half2*)(htb + (r1.x + lane4));
    __half2 h2 = *(const __half2*)(htb + (r2.x + lane4));
    __half2 h3 = *(const __half2*)(htb + (r3.x + lane4));
    float g0 = __uint_as_float(r0.y), g1 = __uint_as_float(r1.y);
    float g2 = __uint_as_float(r2.y), g3 = __uint_as_float(r3.y);
    float2 f0 = __half22float2(h0), f1 = __half22float2(h1);
    float2 f2 = __half22float2(h2), f3 = __half22float2(h3);
    ax += g0 * f0.x; ay += g0 * f0.y;
    bx += g1 * f1.x; by += g1 * f1.y;
    ax += g2 * f2.x; ay += g2 * f2.y;
    bx += g3 * f3.x; by += g3 * f3.y;
  }
  for (; j < c; j++) {
    uint2 r = csr[s + j];
    float g = __uint_as_float(r.y);
    float2 f = __half22float2(*(const __half2*)(htb + (r.x + lane4)));
    ax += g * f.x; ay += g * f.y;
  }
  ax += bx; ay += by;
  float inv = 1.f / (float)(c + 1);
  ax = fmaxf(ax * inv, 0.f);
  ay = fmaxf(ay * inv, 0.f);
  hout[((size_t)node << 6) + lane] = __floats2half2_rn(ax, ay);
}

// ---------------------------------------------------------------------------
extern "C" void kernel_launch(void* const* d_in, const int* in_sizes, int n_in,
                              void* d_out, int out_size, void* d_ws, size_t ws_size,
                              hipStream_t stream) {
  int ob = (out_size + 255) / 256;

  const float *x, *ea, *l1W, *l1b, *l2W, *l2b, *t1W, *t1b, *t2W, *t2b;
  const float *convW[3], *convb[3], *edgew[3];
  const int* ei;

  if (n_in == 20) {          // tuples flattened to separate entries
    x = (const float*)d_in[0]; ei = (const int*)d_in[1]; ea = (const float*)d_in[2];
    for (int l = 0; l < 3; l++) {
      convW[l] = (const float*)d_in[3 + l];
      convb[l] = (const float*)d_in[6 + l];
      edgew[l] = (const float*)d_in[9 + l];
    }
    l1W = (const float*)d_in[12]; l1b = (const float*)d_in[13];
    l2W = (const float*)d_in[14]; l2b = (const float*)d_in[15];
    t1W = (const float*)d_in[16]; t1b = (const float*)d_in[17];
    t2W = (const float*)d_in[18]; t2b = (const float*)d_in[19];
  } else if (n_in == 14) {   // each tuple is ONE concatenated buffer
    x = (const float*)d_in[0]; ei = (const int*)d_in[1]; ea = (const float*)d_in[2];
    const float* cw = (const float*)d_in[3];
    const float* cb = (const float*)d_in[4];
    const float* ew = (const float*)d_in[5];
    for (int l = 0; l < 3; l++) {
      convW[l] = cw + (size_t)l * 128 * 128;
      convb[l] = cb + (size_t)l * 128;
      edgew[l] = ew + l;
    }
    l1W = (const float*)d_in[6];  l1b = (const float*)d_in[7];
    l2W = (const float*)d_in[8];  l2b = (const float*)d_in[9];
    t1W = (const float*)d_in[10]; t1b = (const float*)d_in[11];
    t2W = (const float*)d_in[12]; t2b = (const float*)d_in[13];
  } else {
    sentinel_kernel<<<ob, 256, 0, stream>>>((float*)d_out, out_size,
                                            900.0f + (float)n_in);
    return;
  }

  int n = in_sizes[0] / 129;   // 100000
  int E = in_sizes[2];         // 1600000

  char* ws = (char*)d_ws;
  size_t off = 0;
  auto take = [&](size_t bytes) -> void* {
    void* p = ws + off;
    off = (off + bytes + 255) & ~(size_t)255;
    return p;
  };
  size_t csr_bytes = (size_t)E * 8;
  size_t cnt_bytes = (size_t)n * CNT_STRIDE * 4;
  int*      flag    = (int*)take(256);
  uint2*    csr0    = (uint2*)take(csr_bytes > cnt_bytes ? csr_bytes : cnt_bytes);
  int*      counts  = (int*)csr0;     // alias: counts dead before csr0 written
  uint2*    csr1    = (uint2*)take(csr_bytes);
  uint2*    csr2    = (uint2*)take(csr_bytes);
  int*      starts  = (int*)take(((size_t)n + 1) * 4);
  int*      bsums   = (int*)take(512 * 4);
  float*    tbuf    = (float*)take((size_t)n * 4);
  float*    x0buf   = (float*)take((size_t)n * 4);
  _Float16* h16     = (_Float16*)take((size_t)n * 128 * 2);  // 25.6 MB
  int*      slot    = (int*)h16;      // alias: slot dead before slice writes h16
  _Float16* ht16    = (_Float16*)take((size_t)n * 128 * 2);  // 25.6 MB

  if (off > ws_size) {
    sentinel_kernel<<<ob, 256, 0, stream>>>((float*)d_out, out_size,
                                            1000.0f + (float)(ws_size >> 20));
    return;
  }

  int eb = (E + 255) / 256;
  int nb = (n + 255) / 256;  // 391 <= 512 (scan2 capacity)
  int zb = (n * CNT_STRIDE + 255) / 256;

  init_kernel<<<zb, 256, 0, stream>>>(ei, flag, counts, n);
  rank_kernel<<<eb, 256, 0, stream>>>(ei, E, n, flag, slot, counts);
  scan1_kernel<<<nb, 256, 0, stream>>>(counts, n, starts, bsums);
  scan2_kernel<<<1, 512, 0, stream>>>(bsums, nb, starts + n);
  scan3_kernel<<<nb, 256, 0, stream>>>(starts, bsums, n);
  scatter_kernel<<<(eb + 3) / 4, 256, 0, stream>>>(ei, slot, starts, ea, E, n, flag,
                                                   edgew[0], edgew[1], edgew[2],
                                                   csr0, csr1, csr2);

  int sb = (int)(((size_t)n * 128 + 255) / 256);
  slice_kernel<<<sb, 256, 0, stream>>>(x, h16, x0buf, n);
  // tnet: W1=t1W (129x64), h-rows 1..128, extra=x0 via row 0
  head_mfma_kernel<<<(n + 63) / 64, 256, 0, stream>>>(h16, x0buf, t1W, t1b, t2W, t2b,
                                                      tbuf, n, 1, 0);

  int gemm_grid = min((n + 63) / 64, 1024);
  gemm_mfma_kernel<<<gemm_grid, 256, 0, stream>>>(h16, convW[0], convb[0], ht16, n);
  agg_kernel<<<(n + 3) / 4, 256, 0, stream>>>((const __half2*)ht16, csr0, starts,
                                              edgew[0], (__half2*)h16, n);
  gemm_mfma_kernel<<<gemm_grid, 256, 0, stream>>>(h16, convW[1], convb[1], ht16, n);
  agg_kernel<<<(n + 3) / 4, 256, 0, stream>>>((const __half2*)ht16, csr1, starts,
                                              edgew[1], (__half2*)h16, n);
  gemm_mfma_kernel<<<gemm_grid, 256, 0, stream>>>(h16, convW[2], convb[2], ht16, n);
  agg_kernel<<<(n + 3) / 4, 256, 0, stream>>>((const __half2*)ht16, csr2, starts,
                                              edgew[2], (__half2*)h16, n);

  // mlp: W1=l1W (129x64), h-rows 0..127, extra=t via row 128
  head_mfma_kernel<<<(n + 63) / 64, 256, 0, stream>>>(h16, tbuf, l1W, l1b, l2W, l2b,
                                                      (float*)d_out, n, 0, 128);
}

// Round 6
// 545.930 us; speedup vs baseline: 1.1090x; 1.1090x over previous
//
#include <hip/hip_runtime.h>
#include <hip/hip_fp16.h>
#include <math.h>

// ---------------------------------------------------------------------------
// DeepECCNet: 3-layer gated graph conv + t-gate + MLP head.
// v16: padded atomic counters; 8B packed CSR {src17|g0_15, g1_15|g2_15};
//      agg x8 in-flight. 545.6 us.
// v17: 3x per-layer f32-gate CSR arrays -> REGRESSED +60us (scatter write
//      amplification: 3 dirty lines/edge, WRITE 151MB). Also proved agg
//      VALU-diet neutral => agg is fetch-throughput-bound (~3.4 TB/s L2-miss
//      path), not VALU-bound. v16 record format is optimal: keep it.
// v18: v16 core restored + scan3 removed (scan1 scans n+1 entries; scatter
//      and agg add bsums[i>>8] inline - 1.6KB L1-resident table). One fewer
//      kernel/graph node. Predict scatter ~15-20us, agg 66.2 unchanged,
//      total ~535-540.
// ---------------------------------------------------------------------------

typedef _Float16 f16x8 __attribute__((ext_vector_type(8)));
typedef float f32x4 __attribute__((ext_vector_type(4)));

#define CNT_STRIDE 32  // one counter per 128B line

__device__ __forceinline__ float sigmoidf_(float v) { return 1.f / (1.f + expf(-v)); }

__global__ void sentinel_kernel(float* __restrict__ out, int n, float val) {
  int i = blockIdx.x * 256 + threadIdx.x;
  if (i < n) out[i] = val;
}

// ---- init: zero strided counts (n+1 entries) + detect int64 edge_index -----
__global__ void init_kernel(const int* __restrict__ ei, int* __restrict__ flag,
                            int* __restrict__ counts, int n) {
  int i = blockIdx.x * 256 + threadIdx.x;
  if (i < (n + 1) * CNT_STRIDE) counts[i] = 0;
  if (i == 0) {
    int all0 = 1;
    for (int k = 1; k < 512; k += 2) {
      if (ei[k] != 0) { all0 = 0; break; }
    }
    *flag = all0;
  }
}

// ---- rank: slot[e] = within-target rank via counting atomic ----------------
__global__ void rank_kernel(const int* __restrict__ ei, int E, int n,
                            const int* __restrict__ flag,
                            int* __restrict__ slot, int* __restrict__ counts) {
  int e = blockIdx.x * blockDim.x + threadIdx.x;
  if (e >= E) return;
  int t;
  if (*flag) {
    t = (int)((const long long*)ei)[(size_t)E + e];
  } else {
    t = ei[(size_t)E + e];
  }
  slot[e] = ((unsigned)t < (unsigned)n) ? atomicAdd(&counts[(size_t)t * CNT_STRIDE], 1) : -1;
}

// ---- scan1 over n+1 entries (counts[n]=0 -> starts[n] = prefix) ------------
__global__ void scan1_kernel(const int* __restrict__ counts, int n,
                             int* __restrict__ starts, int* __restrict__ bsums) {
  __shared__ int tmp[256];
  int i = blockIdx.x * 256 + threadIdx.x;
  int v = (i <= n) ? counts[(size_t)i * CNT_STRIDE] : 0;
  tmp[threadIdx.x] = v;
  __syncthreads();
  for (int off = 1; off < 256; off <<= 1) {
    int t = (threadIdx.x >= (unsigned)off) ? tmp[threadIdx.x - off] : 0;
    __syncthreads();
    tmp[threadIdx.x] += t;
    __syncthreads();
  }
  if (i <= n) starts[i] = tmp[threadIdx.x] - v;  // block-local exclusive
  if (threadIdx.x == 255) bsums[blockIdx.x] = tmp[255];
}

__global__ void scan2_kernel(int* __restrict__ bsums, int nb) {
  __shared__ int tmp[512];
  int v = (threadIdx.x < (unsigned)nb) ? bsums[threadIdx.x] : 0;
  tmp[threadIdx.x] = v;
  __syncthreads();
  for (int off = 1; off < 512; off <<= 1) {
    int t = (threadIdx.x >= (unsigned)off) ? tmp[threadIdx.x - off] : 0;
    __syncthreads();
    tmp[threadIdx.x] += t;
    __syncthreads();
  }
  if (threadIdx.x < (unsigned)nb) bsums[threadIdx.x] = tmp[threadIdx.x] - v;  // exclusive
}

// ---- scatter: csr[starts[t]+bsums[t>>8]+rank] = {src|g0, g1|g2} (8B) -------
__global__ void scatter_kernel(const int* __restrict__ ei, const int* __restrict__ slot,
                               const int* __restrict__ starts,
                               const int* __restrict__ bsums,
                               const float* __restrict__ ea, int E, int n,
                               const int* __restrict__ flag,
                               const float* __restrict__ w0p,
                               const float* __restrict__ w1p,
                               const float* __restrict__ w2p,
                               uint2* __restrict__ csr) {
  float w0 = w0p[0], w1 = w1p[0], w2 = w2p[0];
  int f64 = *flag;
  const long long* e64 = (const long long*)ei;
  int base = blockIdx.x * blockDim.x + threadIdx.x;
  int stride = gridDim.x * blockDim.x;
#pragma unroll
  for (int u = 0; u < 4; u++) {
    int e = base + u * stride;
    if (e < E) {
      int sl = slot[e];
      if (sl >= 0) {
        int s, t;
        if (f64) {
          s = (int)e64[e];
          t = (int)e64[(size_t)E + e];
        } else {
          s = ei[e];
          t = ei[(size_t)E + e];
        }
        int pos = starts[t] + bsums[t >> 8] + sl;
        if ((unsigned)pos < (unsigned)E) {
          float a = ea[e];
          unsigned sn = (unsigned)min(max(s, 0), min(n - 1, 0x1ffff));
          unsigned g0 = (unsigned)__float2uint_rn(sigmoidf_(a * w0) * 32767.f);
          unsigned g1 = (unsigned)__float2uint_rn(sigmoidf_(a * w1) * 32767.f);
          unsigned g2 = (unsigned)__float2uint_rn(sigmoidf_(a * w2) * 32767.f);
          csr[pos] = make_uint2(sn | (g0 << 17), g1 | (g2 << 15));
        }
      }
    }
  }
}

// ---- h0 = fp16(x[:, 1:]); x0 = x[:, 0] -------------------------------------
__global__ void slice_kernel(const float* __restrict__ x, _Float16* __restrict__ h,
                             float* __restrict__ x0, int n) {
  int idx = blockIdx.x * blockDim.x + threadIdx.x;
  if (idx < n * 128) {
    int node = idx >> 7;
    int k = idx & 127;
    h[idx] = (_Float16)x[(size_t)node * 129 + 1 + k];
  }
  if (idx < n) x0[idx] = x[(size_t)idx * 129];
}

// ---- unified MFMA head: out = sigmoid( relu(h@W1[hrow0:hrow0+128] +
//        extra*W1[xrow] + b1) @ w2 + b2 )
__global__ __launch_bounds__(256) void head_mfma_kernel(const _Float16* __restrict__ h,
    const float* __restrict__ extra, const float* __restrict__ W1,
    const float* __restrict__ b1, const float* __restrict__ w2,
    const float* __restrict__ b2, float* __restrict__ out, int n,
    int hrow0, int xrow) {
  __shared__ __align__(16) _Float16 sB[4 * 4 * 64 * 8];  // 16 KB, B-frag order
  __shared__ float sWx[64], sB1[64], sW2[64];
  for (int idx = threadIdx.x; idx < 8192; idx += 256) {
    int k = idx >> 6, col = idx & 63;
    float w = W1[(size_t)(hrow0 + k) * 64 + col];
    int ks = k >> 5, quad = (k >> 3) & 3, j = k & 7;
    int nt = col >> 4, cl = col & 15;
    sB[(((ks * 4 + nt) * 64) + quad * 16 + cl) * 8 + j] = (_Float16)w;
  }
  if (threadIdx.x < 64) {
    sWx[threadIdx.x] = W1[(size_t)xrow * 64 + threadIdx.x];
    sB1[threadIdx.x] = b1[threadIdx.x];
    sW2[threadIdx.x] = w2[threadIdx.x];
  }
  __syncthreads();
  int wv = threadIdx.x >> 6, lane = threadIdx.x & 63;
  int quad = lane >> 4, l15 = lane & 15;
  int n0 = (blockIdx.x * 4 + wv) * 16;
  if (n0 >= n) return;
  int node_a = min(n0 + l15, n - 1);
  const _Float16* hrow = h + (size_t)node_a * 128 + quad * 8;

  f32x4 acc[4];
#pragma unroll
  for (int t = 0; t < 4; t++) acc[t] = (f32x4){0.f, 0.f, 0.f, 0.f};
  for (int ks = 0; ks < 4; ks++) {
    f16x8 afrag = *(const f16x8*)(hrow + ks * 32);
    const f16x8* bp = (const f16x8*)sB;
#pragma unroll
    for (int t = 0; t < 4; t++) {
      f16x8 bfrag = bp[(ks * 4 + t) * 64 + lane];
      acc[t] = __builtin_amdgcn_mfma_f32_16x16x32_f16(afrag, bfrag, acc[t], 0, 0, 0);
    }
  }
  float b2v = b2[0];
  float xv[4], part[4] = {0.f, 0.f, 0.f, 0.f};
#pragma unroll
  for (int r = 0; r < 4; r++) xv[r] = extra[min(n0 + quad * 4 + r, n - 1)];
#pragma unroll
  for (int t = 0; t < 4; t++) {
    int col = t * 16 + l15;
    float wx = sWx[col], bb = sB1[col], w2v = sW2[col];
#pragma unroll
    for (int r = 0; r < 4; r++) {
      float u = fmaxf(acc[t][r] + xv[r] * wx + bb, 0.f);
      part[r] += u * w2v;
    }
  }
#pragma unroll
  for (int r = 0; r < 4; r++) {
    float p = part[r];
    p += __shfl_xor(p, 1); p += __shfl_xor(p, 2);
    p += __shfl_xor(p, 4); p += __shfl_xor(p, 8);
    int node = n0 + quad * 4 + r;
    if (l15 == 0 && node < n) out[node] = sigmoidf_(p + b2v);
  }
}

// ---- MFMA GEMM: ht16 = f16(h16 @ W + b); grid-stride over 64-node tiles ----
__global__ __launch_bounds__(256) void gemm_mfma_kernel(const _Float16* __restrict__ h,
    const float* __restrict__ Wg, const float* __restrict__ b,
    _Float16* __restrict__ out16, int n) {
  __shared__ __align__(16) _Float16 sB[4 * 8 * 64 * 8];  // 32 KB
  for (int i = threadIdx.x; i < 4096; i += 256) {  // i = float4 index over W
    int k = i >> 5;
    int n4 = (i & 31) * 4;
    float4 w4 = ((const float4*)Wg)[i];
    int ks = k >> 5, quad = (k >> 3) & 3, j = k & 7;
#pragma unroll
    for (int c = 0; c < 4; c++) {
      int col = n4 + c;
      int nt = col >> 4, cl = col & 15;
      sB[(((ks * 8 + nt) * 64) + quad * 16 + cl) * 8 + j] =
          (_Float16)((const float*)&w4)[c];
    }
  }
  __syncthreads();
  int wv = threadIdx.x >> 6, lane = threadIdx.x & 63;
  int quad = lane >> 4, l15 = lane & 15;
  int tiles = (n + 63) >> 6;
  for (int tile = blockIdx.x; tile < tiles; tile += gridDim.x) {
    int n0 = (tile * 4 + wv) * 16;
    if (n0 >= n) continue;
    int node_a = min(n0 + l15, n - 1);
    const _Float16* hrow = h + (size_t)node_a * 128 + quad * 8;

    f32x4 acc[8];
#pragma unroll
    for (int t = 0; t < 8; t++) acc[t] = (f32x4){0.f, 0.f, 0.f, 0.f};

    for (int ks = 0; ks < 4; ks++) {
      f16x8 afrag = *(const f16x8*)(hrow + ks * 32);
      const f16x8* bp = (const f16x8*)(sB + ks * 8 * 64 * 8);
#pragma unroll
      for (int t = 0; t < 8; t++) {
        f16x8 bfrag = bp[t * 64 + lane];
        acc[t] = __builtin_amdgcn_mfma_f32_16x16x32_f16(afrag, bfrag, acc[t], 0, 0, 0);
      }
    }
#pragma unroll
    for (int t = 0; t < 8; t++) {
      float bias = b[t * 16 + l15];
#pragma unroll
      for (int r = 0; r < 4; r++) {
        int node = n0 + quad * 4 + r;
        if (node < n)
          out16[(size_t)node * 128 + t * 16 + l15] = (_Float16)(acc[t][r] + bias);
      }
    }
  }
}

// ---- aggregation: fp16 rows, packed 8B records, x8 -> x4 -> serial tail ----
// h' = f16( relu( (gs*ht[v] + sum_e g_e*ht[src_e]) / (deg+1) ) )
// segment bounds: starts[i] + bsums[i>>8] (scan3 folded in).
template <int LAYER>
__device__ __forceinline__ float gate_(uint2 r) {
  const float inv = 1.f / 32767.f;
  if (LAYER == 0) return (float)(r.x >> 17) * inv;
  if (LAYER == 1) return (float)(r.y & 0x7fffu) * inv;
  return (float)(r.y >> 15) * inv;
}

template <int LAYER>
__global__ __launch_bounds__(256) void agg_kernel(const __half2* __restrict__ ht,
    const uint2* __restrict__ csr, const int* __restrict__ starts,
    const int* __restrict__ bsums, const float* __restrict__ wp,
    __half2* __restrict__ hout, int n) {
  int wv = threadIdx.x >> 6, lane = threadIdx.x & 63;
  int node = blockIdx.x * 4 + wv;
  if (node >= n) return;
  int s = starts[node] + bsums[node >> 8];
  int c = starts[node + 1] + bsums[(node + 1) >> 8] - s;
  float gs = sigmoidf_(wp[0]);
  const __half2* htl = ht + lane;
  float2 v0 = __half22float2(htl[(size_t)node << 6]);
  float ax = gs * v0.x, ay = gs * v0.y;
  float bx = 0.f, by = 0.f;
  int j = 0;
  for (; j + 8 <= c; j += 8) {
    uint2 r0 = csr[s + j],     r1 = csr[s + j + 1];
    uint2 r2 = csr[s + j + 2], r3 = csr[s + j + 3];
    uint2 r4 = csr[s + j + 4], r5 = csr[s + j + 5];
    uint2 r6 = csr[s + j + 6], r7 = csr[s + j + 7];
    __half2 h0 = htl[(size_t)(r0.x & 0x1ffffu) << 6];
    __half2 h1 = htl[(size_t)(r1.x & 0x1ffffu) << 6];
    __half2 h2 = htl[(size_t)(r2.x & 0x1ffffu) << 6];
    __half2 h3 = htl[(size_t)(r3.x & 0x1ffffu) << 6];
    __half2 h4 = htl[(size_t)(r4.x & 0x1ffffu) << 6];
    __half2 h5 = htl[(size_t)(r5.x & 0x1ffffu) << 6];
    __half2 h6 = htl[(size_t)(r6.x & 0x1ffffu) << 6];
    __half2 h7 = htl[(size_t)(r7.x & 0x1ffffu) << 6];
    float g0 = gate_<LAYER>(r0), g1 = gate_<LAYER>(r1);
    float g2 = gate_<LAYER>(r2), g3 = gate_<LAYER>(r3);
    float g4 = gate_<LAYER>(r4), g5 = gate_<LAYER>(r5);
    float g6 = gate_<LAYER>(r6), g7 = gate_<LAYER>(r7);
    float2 f0 = __half22float2(h0), f1 = __half22float2(h1);
    float2 f2 = __half22float2(h2), f3 = __half22float2(h3);
    float2 f4 = __half22float2(h4), f5 = __half22float2(h5);
    float2 f6 = __half22float2(h6), f7 = __half22float2(h7);
    ax += g0 * f0.x; ay += g0 * f0.y;
    bx += g1 * f1.x; by += g1 * f1.y;
    ax += g2 * f2.x; ay += g2 * f2.y;
    bx += g3 * f3.x; by += g3 * f3.y;
    ax += g4 * f4.x; ay += g4 * f4.y;
    bx += g5 * f5.x; by += g5 * f5.y;
    ax += g6 * f6.x; ay += g6 * f6.y;
    bx += g7 * f7.x; by += g7 * f7.y;
  }
  for (; j + 4 <= c; j += 4) {
    uint2 r0 = csr[s + j],     r1 = csr[s + j + 1];
    uint2 r2 = csr[s + j + 2], r3 = csr[s + j + 3];
    __half2 h0 = htl[(size_t)(r0.x & 0x1ffffu) << 6];
    __half2 h1 = htl[(size_t)(r1.x & 0x1ffffu) << 6];
    __half2 h2 = htl[(size_t)(r2.x & 0x1ffffu) << 6];
    __half2 h3 = htl[(size_t)(r3.x & 0x1ffffu) << 6];
    float g0 = gate_<LAYER>(r0), g1 = gate_<LAYER>(r1);
    float g2 = gate_<LAYER>(r2), g3 = gate_<LAYER>(r3);
    float2 f0 = __half22float2(h0), f1 = __half22float2(h1);
    float2 f2 = __half22float2(h2), f3 = __half22float2(h3);
    ax += g0 * f0.x; ay += g0 * f0.y;
    bx += g1 * f1.x; by += g1 * f1.y;
    ax += g2 * f2.x; ay += g2 * f2.y;
    bx += g3 * f3.x; by += g3 * f3.y;
  }
  for (; j < c; j++) {
    uint2 r = csr[s + j];
    int sn = r.x & 0x1ffffu;
    float g = gate_<LAYER>(r);
    float2 f = __half22float2(htl[(size_t)sn << 6]);
    ax += g * f.x; ay += g * f.y;
  }
  ax += bx; ay += by;
  float inv = 1.f / (float)(c + 1);
  ax = fmaxf(ax * inv, 0.f);
  ay = fmaxf(ay * inv, 0.f);
  hout[((size_t)node << 6) + lane] = __floats2half2_rn(ax, ay);
}

// ---------------------------------------------------------------------------
extern "C" void kernel_launch(void* const* d_in, const int* in_sizes, int n_in,
                              void* d_out, int out_size, void* d_ws, size_t ws_size,
                              hipStream_t stream) {
  int ob = (out_size + 255) / 256;

  const float *x, *ea, *l1W, *l1b, *l2W, *l2b, *t1W, *t1b, *t2W, *t2b;
  const float *convW[3], *convb[3], *edgew[3];
  const int* ei;

  if (n_in == 20) {          // tuples flattened to separate entries
    x = (const float*)d_in[0]; ei = (const int*)d_in[1]; ea = (const float*)d_in[2];
    for (int l = 0; l < 3; l++) {
      convW[l] = (const float*)d_in[3 + l];
      convb[l] = (const float*)d_in[6 + l];
      edgew[l] = (const float*)d_in[9 + l];
    }
    l1W = (const float*)d_in[12]; l1b = (const float*)d_in[13];
    l2W = (const float*)d_in[14]; l2b = (const float*)d_in[15];
    t1W = (const float*)d_in[16]; t1b = (const float*)d_in[17];
    t2W = (const float*)d_in[18]; t2b = (const float*)d_in[19];
  } else if (n_in == 14) {   // each tuple is ONE concatenated buffer
    x = (const float*)d_in[0]; ei = (const int*)d_in[1]; ea = (const float*)d_in[2];
    const float* cw = (const float*)d_in[3];
    const float* cb = (const float*)d_in[4];
    const float* ew = (const float*)d_in[5];
    for (int l = 0; l < 3; l++) {
      convW[l] = cw + (size_t)l * 128 * 128;
      convb[l] = cb + (size_t)l * 128;
      edgew[l] = ew + l;
    }
    l1W = (const float*)d_in[6];  l1b = (const float*)d_in[7];
    l2W = (const float*)d_in[8];  l2b = (const float*)d_in[9];
    t1W = (const float*)d_in[10]; t1b = (const float*)d_in[11];
    t2W = (const float*)d_in[12]; t2b = (const float*)d_in[13];
  } else {
    sentinel_kernel<<<ob, 256, 0, stream>>>((float*)d_out, out_size,
                                            900.0f + (float)n_in);
    return;
  }

  int n = in_sizes[0] / 129;   // 100000
  int E = in_sizes[2];         // 1600000

  char* ws = (char*)d_ws;
  size_t off = 0;
  auto take = [&](size_t bytes) -> void* {
    void* p = ws + off;
    off = (off + bytes + 255) & ~(size_t)255;
    return p;
  };
  size_t csr_bytes = (size_t)E * 8;
  size_t cnt_bytes = ((size_t)n + 1) * CNT_STRIDE * 4;
  int*      flag    = (int*)take(256);
  uint2*    csr     = (uint2*)take(csr_bytes > cnt_bytes ? csr_bytes : cnt_bytes);
  int*      counts  = (int*)csr;      // alias: counts dead before csr written
  int*      starts  = (int*)take(((size_t)n + 1) * 4);
  int*      bsums   = (int*)take(512 * 4);
  float*    tbuf    = (float*)take((size_t)n * 4);
  float*    x0buf   = (float*)take((size_t)n * 4);
  int*      slot    = (int*)take((size_t)E * 4);             // 6.4 MB
  _Float16* h16     = (_Float16*)take((size_t)n * 128 * 2);  // 25.6 MB
  _Float16* ht16    = (_Float16*)take((size_t)n * 128 * 2);  // 25.6 MB

  if (off > ws_size) {
    sentinel_kernel<<<ob, 256, 0, stream>>>((float*)d_out, out_size,
                                            1000.0f + (float)(ws_size >> 20));
    return;
  }

  int eb = (E + 255) / 256;
  int nb1 = (n + 1 + 255) / 256;  // scan1 covers n+1 entries; 392 <= 512
  int zb = ((n + 1) * CNT_STRIDE + 255) / 256;

  init_kernel<<<zb, 256, 0, stream>>>(ei, flag, counts, n);
  rank_kernel<<<eb, 256, 0, stream>>>(ei, E, n, flag, slot, counts);
  scan1_kernel<<<nb1, 256, 0, stream>>>(counts, n, starts, bsums);
  scan2_kernel<<<1, 512, 0, stream>>>(bsums, nb1);
  scatter_kernel<<<(eb + 3) / 4, 256, 0, stream>>>(ei, slot, starts, bsums, ea, E, n,
                                                   flag, edgew[0], edgew[1], edgew[2],
                                                   csr);

  int sb = (int)(((size_t)n * 128 + 255) / 256);
  slice_kernel<<<sb, 256, 0, stream>>>(x, h16, x0buf, n);
  // tnet: W1=t1W (129x64), h-rows 1..128, extra=x0 via row 0
  head_mfma_kernel<<<(n + 63) / 64, 256, 0, stream>>>(h16, x0buf, t1W, t1b, t2W, t2b,
                                                      tbuf, n, 1, 0);

  int gemm_grid = min((n + 63) / 64, 1024);
  gemm_mfma_kernel<<<gemm_grid, 256, 0, stream>>>(h16, convW[0], convb[0], ht16, n);
  agg_kernel<0><<<(n + 3) / 4, 256, 0, stream>>>((const __half2*)ht16, csr, starts,
                                                 bsums, edgew[0], (__half2*)h16, n);
  gemm_mfma_kernel<<<gemm_grid, 256, 0, stream>>>(h16, convW[1], convb[1], ht16, n);
  agg_kernel<1><<<(n + 3) / 4, 256, 0, stream>>>((const __half2*)ht16, csr, starts,
                                                 bsums, edgew[1], (__half2*)h16, n);
  gemm_mfma_kernel<<<gemm_grid, 256, 0, stream>>>(h16, convW[2], convb[2], ht16, n);
  agg_kernel<2><<<(n + 3) / 4, 256, 0, stream>>>((const __half2*)ht16, csr, starts,
                                                 bsums, edgew[2], (__half2*)h16, n);

  // mlp: W1=l1W (129x64), h-rows 0..127, extra=t via row 128
  head_mfma_kernel<<<(n + 63) / 64, 256, 0, stream>>>(h16, tbuf, l1W, l1b, l2W, l2b,
                                                      (float*)d_out, n, 0, 128);
}

// Round 8
// 508.560 us; speedup vs baseline: 1.1905x; 1.0735x over previous
//
#include <hip/hip_runtime.h>
#include <hip/hip_fp16.h>
#include <math.h>

// ---------------------------------------------------------------------------
// DeepECCNet: 3-layer gated graph conv + t-gate + MLP head.
// v16/v18: 545.6/545.9 us. agg = 3x66.5us, FETCH 192MB = ht16(25.6MB) x ~7
//      XCD-dup + csr 12.8MB -> L2 caching already ideal; agg is fetch-BYTE
//      bound (x8 widening +8% only, VALU-diet neutral, time tracks bytes).
// v19: int8 gather rows. gemm epilogue quantizes ht rows to 128xu8 with
//      per-row absmax scale (offset-binary, scales[] f32 400KB L2-resident).
//      agg: edge-PAIR structure (half-wave per edge, lane = 4 elems/dword),
//      decode u8 via cvt_f32_ubyte idiom, -128 correction folded into
//      128*sum(g*scale). Halves VMEM instrs + row bytes. Predict agg
//      FETCH ~105MB, 66.5 -> ~44us; total ~485. Risk: absmax +~0.002.
// v20: identical resubmission of v19 — R7 bench was an infrastructure
//      failure (container died twice); theory untested, prediction live.
// ---------------------------------------------------------------------------

typedef _Float16 f16x8 __attribute__((ext_vector_type(8)));
typedef float f32x4 __attribute__((ext_vector_type(4)));

#define CNT_STRIDE 32  // one counter per 128B line

__device__ __forceinline__ float sigmoidf_(float v) { return 1.f / (1.f + expf(-v)); }

__global__ void sentinel_kernel(float* __restrict__ out, int n, float val) {
  int i = blockIdx.x * 256 + threadIdx.x;
  if (i < n) out[i] = val;
}

// ---- init: zero strided counts (n+1 entries) + detect int64 edge_index -----
__global__ void init_kernel(const int* __restrict__ ei, int* __restrict__ flag,
                            int* __restrict__ counts, int n) {
  int i = blockIdx.x * 256 + threadIdx.x;
  if (i < (n + 1) * CNT_STRIDE) counts[i] = 0;
  if (i == 0) {
    int all0 = 1;
    for (int k = 1; k < 512; k += 2) {
      if (ei[k] != 0) { all0 = 0; break; }
    }
    *flag = all0;
  }
}

// ---- rank: slot[e] = within-target rank via counting atomic ----------------
__global__ void rank_kernel(const int* __restrict__ ei, int E, int n,
                            const int* __restrict__ flag,
                            int* __restrict__ slot, int* __restrict__ counts) {
  int e = blockIdx.x * blockDim.x + threadIdx.x;
  if (e >= E) return;
  int t;
  if (*flag) {
    t = (int)((const long long*)ei)[(size_t)E + e];
  } else {
    t = ei[(size_t)E + e];
  }
  slot[e] = ((unsigned)t < (unsigned)n) ? atomicAdd(&counts[(size_t)t * CNT_STRIDE], 1) : -1;
}

// ---- scan1 over n+1 entries ------------------------------------------------
__global__ void scan1_kernel(const int* __restrict__ counts, int n,
                             int* __restrict__ starts, int* __restrict__ bsums) {
  __shared__ int tmp[256];
  int i = blockIdx.x * 256 + threadIdx.x;
  int v = (i <= n) ? counts[(size_t)i * CNT_STRIDE] : 0;
  tmp[threadIdx.x] = v;
  __syncthreads();
  for (int off = 1; off < 256; off <<= 1) {
    int t = (threadIdx.x >= (unsigned)off) ? tmp[threadIdx.x - off] : 0;
    __syncthreads();
    tmp[threadIdx.x] += t;
    __syncthreads();
  }
  if (i <= n) starts[i] = tmp[threadIdx.x] - v;  // block-local exclusive
  if (threadIdx.x == 255) bsums[blockIdx.x] = tmp[255];
}

__global__ void scan2_kernel(int* __restrict__ bsums, int nb) {
  __shared__ int tmp[512];
  int v = (threadIdx.x < (unsigned)nb) ? bsums[threadIdx.x] : 0;
  tmp[threadIdx.x] = v;
  __syncthreads();
  for (int off = 1; off < 512; off <<= 1) {
    int t = (threadIdx.x >= (unsigned)off) ? tmp[threadIdx.x - off] : 0;
    __syncthreads();
    tmp[threadIdx.x] += t;
    __syncthreads();
  }
  if (threadIdx.x < (unsigned)nb) bsums[threadIdx.x] = tmp[threadIdx.x] - v;  // exclusive
}

// ---- scatter: csr[starts[t]+bsums[t>>8]+rank] = {src|g0, g1|g2} (8B) -------
__global__ void scatter_kernel(const int* __restrict__ ei, const int* __restrict__ slot,
                               const int* __restrict__ starts,
                               const int* __restrict__ bsums,
                               const float* __restrict__ ea, int E, int n,
                               const int* __restrict__ flag,
                               const float* __restrict__ w0p,
                               const float* __restrict__ w1p,
                               const float* __restrict__ w2p,
                               uint2* __restrict__ csr) {
  float w0 = w0p[0], w1 = w1p[0], w2 = w2p[0];
  int f64 = *flag;
  const long long* e64 = (const long long*)ei;
  int base = blockIdx.x * blockDim.x + threadIdx.x;
  int stride = gridDim.x * blockDim.x;
#pragma unroll
  for (int u = 0; u < 4; u++) {
    int e = base + u * stride;
    if (e < E) {
      int sl = slot[e];
      if (sl >= 0) {
        int s, t;
        if (f64) {
          s = (int)e64[e];
          t = (int)e64[(size_t)E + e];
        } else {
          s = ei[e];
          t = ei[(size_t)E + e];
        }
        int pos = starts[t] + bsums[t >> 8] + sl;
        if ((unsigned)pos < (unsigned)E) {
          float a = ea[e];
          unsigned sn = (unsigned)min(max(s, 0), min(n - 1, 0x1ffff));
          unsigned g0 = (unsigned)__float2uint_rn(sigmoidf_(a * w0) * 32767.f);
          unsigned g1 = (unsigned)__float2uint_rn(sigmoidf_(a * w1) * 32767.f);
          unsigned g2 = (unsigned)__float2uint_rn(sigmoidf_(a * w2) * 32767.f);
          csr[pos] = make_uint2(sn | (g0 << 17), g1 | (g2 << 15));
        }
      }
    }
  }
}

// ---- h0 = fp16(x[:, 1:]); x0 = x[:, 0] -------------------------------------
__global__ void slice_kernel(const float* __restrict__ x, _Float16* __restrict__ h,
                             float* __restrict__ x0, int n) {
  int idx = blockIdx.x * blockDim.x + threadIdx.x;
  if (idx < n * 128) {
    int node = idx >> 7;
    int k = idx & 127;
    h[idx] = (_Float16)x[(size_t)node * 129 + 1 + k];
  }
  if (idx < n) x0[idx] = x[(size_t)idx * 129];
}

// ---- unified MFMA head: out = sigmoid( relu(h@W1[hrow0:hrow0+128] +
//        extra*W1[xrow] + b1) @ w2 + b2 )
__global__ __launch_bounds__(256) void head_mfma_kernel(const _Float16* __restrict__ h,
    const float* __restrict__ extra, const float* __restrict__ W1,
    const float* __restrict__ b1, const float* __restrict__ w2,
    const float* __restrict__ b2, float* __restrict__ out, int n,
    int hrow0, int xrow) {
  __shared__ __align__(16) _Float16 sB[4 * 4 * 64 * 8];  // 16 KB, B-frag order
  __shared__ float sWx[64], sB1[64], sW2[64];
  for (int idx = threadIdx.x; idx < 8192; idx += 256) {
    int k = idx >> 6, col = idx & 63;
    float w = W1[(size_t)(hrow0 + k) * 64 + col];
    int ks = k >> 5, quad = (k >> 3) & 3, j = k & 7;
    int nt = col >> 4, cl = col & 15;
    sB[(((ks * 4 + nt) * 64) + quad * 16 + cl) * 8 + j] = (_Float16)w;
  }
  if (threadIdx.x < 64) {
    sWx[threadIdx.x] = W1[(size_t)xrow * 64 + threadIdx.x];
    sB1[threadIdx.x] = b1[threadIdx.x];
    sW2[threadIdx.x] = w2[threadIdx.x];
  }
  __syncthreads();
  int wv = threadIdx.x >> 6, lane = threadIdx.x & 63;
  int quad = lane >> 4, l15 = lane & 15;
  int n0 = (blockIdx.x * 4 + wv) * 16;
  if (n0 >= n) return;
  int node_a = min(n0 + l15, n - 1);
  const _Float16* hrow = h + (size_t)node_a * 128 + quad * 8;

  f32x4 acc[4];
#pragma unroll
  for (int t = 0; t < 4; t++) acc[t] = (f32x4){0.f, 0.f, 0.f, 0.f};
  for (int ks = 0; ks < 4; ks++) {
    f16x8 afrag = *(const f16x8*)(hrow + ks * 32);
    const f16x8* bp = (const f16x8*)sB;
#pragma unroll
    for (int t = 0; t < 4; t++) {
      f16x8 bfrag = bp[(ks * 4 + t) * 64 + lane];
      acc[t] = __builtin_amdgcn_mfma_f32_16x16x32_f16(afrag, bfrag, acc[t], 0, 0, 0);
    }
  }
  float b2v = b2[0];
  float xv[4], part[4] = {0.f, 0.f, 0.f, 0.f};
#pragma unroll
  for (int r = 0; r < 4; r++) xv[r] = extra[min(n0 + quad * 4 + r, n - 1)];
#pragma unroll
  for (int t = 0; t < 4; t++) {
    int col = t * 16 + l15;
    float wx = sWx[col], bb = sB1[col], w2v = sW2[col];
#pragma unroll
    for (int r = 0; r < 4; r++) {
      float u = fmaxf(acc[t][r] + xv[r] * wx + bb, 0.f);
      part[r] += u * w2v;
    }
  }
#pragma unroll
  for (int r = 0; r < 4; r++) {
    float p = part[r];
    p += __shfl_xor(p, 1); p += __shfl_xor(p, 2);
    p += __shfl_xor(p, 4); p += __shfl_xor(p, 8);
    int node = n0 + quad * 4 + r;
    if (l15 == 0 && node < n) out[node] = sigmoidf_(p + b2v);
  }
}

// ---- MFMA GEMM: ht8/scales = rowquant(h16 @ W + b) -------------------------
// int8 offset-binary: u = rint(v*127/rowmax)+128; decode v=(u-128)*rowmax/127
__global__ __launch_bounds__(256) void gemm_mfma_kernel(const _Float16* __restrict__ h,
    const float* __restrict__ Wg, const float* __restrict__ b,
    unsigned char* __restrict__ out8, float* __restrict__ scales, int n) {
  __shared__ __align__(16) _Float16 sB[4 * 8 * 64 * 8];  // 32 KB
  for (int i = threadIdx.x; i < 4096; i += 256) {  // i = float4 index over W
    int k = i >> 5;
    int n4 = (i & 31) * 4;
    float4 w4 = ((const float4*)Wg)[i];
    int ks = k >> 5, quad = (k >> 3) & 3, j = k & 7;
#pragma unroll
    for (int c = 0; c < 4; c++) {
      int col = n4 + c;
      int nt = col >> 4, cl = col & 15;
      sB[(((ks * 8 + nt) * 64) + quad * 16 + cl) * 8 + j] =
          (_Float16)((const float*)&w4)[c];
    }
  }
  __syncthreads();
  int wv = threadIdx.x >> 6, lane = threadIdx.x & 63;
  int quad = lane >> 4, l15 = lane & 15;
  int tiles = (n + 63) >> 6;
  for (int tile = blockIdx.x; tile < tiles; tile += gridDim.x) {
    int n0 = (tile * 4 + wv) * 16;
    if (n0 >= n) continue;
    int node_a = min(n0 + l15, n - 1);
    const _Float16* hrow = h + (size_t)node_a * 128 + quad * 8;

    f32x4 acc[8];
#pragma unroll
    for (int t = 0; t < 8; t++) acc[t] = (f32x4){0.f, 0.f, 0.f, 0.f};

    for (int ks = 0; ks < 4; ks++) {
      f16x8 afrag = *(const f16x8*)(hrow + ks * 32);
      const f16x8* bp = (const f16x8*)(sB + ks * 8 * 64 * 8);
#pragma unroll
      for (int t = 0; t < 8; t++) {
        f16x8 bfrag = bp[t * 64 + lane];
        acc[t] = __builtin_amdgcn_mfma_f32_16x16x32_f16(afrag, bfrag, acc[t], 0, 0, 0);
      }
    }
    // add bias in place, then per-row absmax (row = 16 l15-lanes x 8 t-cols)
#pragma unroll
    for (int t = 0; t < 8; t++) {
      float bias = b[t * 16 + l15];
#pragma unroll
      for (int r = 0; r < 4; r++) acc[t][r] += bias;
    }
    float mx[4] = {0.f, 0.f, 0.f, 0.f};
#pragma unroll
    for (int t = 0; t < 8; t++)
#pragma unroll
      for (int r = 0; r < 4; r++) mx[r] = fmaxf(mx[r], fabsf(acc[t][r]));
#pragma unroll
    for (int m = 1; m <= 8; m <<= 1) {
#pragma unroll
      for (int r = 0; r < 4; r++) mx[r] = fmaxf(mx[r], __shfl_xor(mx[r], m));
    }
#pragma unroll
    for (int r = 0; r < 4; r++) {
      int node = n0 + quad * 4 + r;
      if (node >= n) continue;
      float inv = (mx[r] > 0.f) ? 127.f / mx[r] : 0.f;
      if (l15 == 0) scales[node] = mx[r] * (1.f / 127.f);
#pragma unroll
      for (int t = 0; t < 8; t++) {
        int u = (int)rintf(acc[t][r] * inv) + 128;
        u = min(max(u, 0), 255);
        out8[(size_t)node * 128 + t * 16 + l15] = (unsigned char)u;
      }
    }
  }
}

// ---- aggregation: int8 rows + per-row scales, edge-pair halves -------------
// h' = f16( relu( (gs*ht[v] + sum_e g_e*ht[src_e]) / (deg+1) ) )
// lane: p = lane>>5 selects even/odd edge of a pair; sub = lane&31 covers
// 4 elements (one dword of the 128B int8 row). Decode folds -128 into corr.
template <int LAYER>
__device__ __forceinline__ float gate_(uint2 r) {
  const float inv = 1.f / 32767.f;
  if (LAYER == 0) return (float)(r.x >> 17) * inv;
  if (LAYER == 1) return (float)(r.y & 0x7fffu) * inv;
  return (float)(r.y >> 15) * inv;
}

#define ACC4(u, g)                                   \
  a0 += (float)((u) & 0xffu) * (g);                  \
  a1 += (float)(((u) >> 8) & 0xffu) * (g);           \
  a2 += (float)(((u) >> 16) & 0xffu) * (g);          \
  a3 += (float)((u) >> 24) * (g);

template <int LAYER>
__global__ __launch_bounds__(256) void agg_kernel(const unsigned char* __restrict__ ht8,
    const float* __restrict__ scales, const uint2* __restrict__ csr,
    const int* __restrict__ starts, const int* __restrict__ bsums,
    const float* __restrict__ wp, __half2* __restrict__ hout, int n) {
  int wv = threadIdx.x >> 6, lane = threadIdx.x & 63;
  int node = blockIdx.x * 4 + wv;
  if (node >= n) return;
  int s = starts[node] + bsums[node >> 8];
  int c = starts[node + 1] + bsums[(node + 1) >> 8] - s;
  float gs = sigmoidf_(wp[0]);
  int sub = lane & 31, p = lane >> 5;
  unsigned sub4 = (unsigned)sub * 4u;

  // self term: half 0 only (half 1 gets g=0)
  unsigned su = *(const unsigned*)(ht8 + (unsigned)node * 128u + sub4);
  float gsc = (p == 0) ? gs * scales[node] : 0.f;
  float sgs = gsc;
  float a0 = 0.f, a1 = 0.f, a2 = 0.f, a3 = 0.f;
  ACC4(su, gsc)

  int j = 0;
  for (; j + 8 <= c; j += 8) {   // 4 pairs: half p handles j+2q+p
    uint2 r0 = csr[s + j + 0 + p], r1 = csr[s + j + 2 + p];
    uint2 r2 = csr[s + j + 4 + p], r3 = csr[s + j + 6 + p];
    unsigned i0 = r0.x & 0x1ffffu, i1 = r1.x & 0x1ffffu;
    unsigned i2 = r2.x & 0x1ffffu, i3 = r3.x & 0x1ffffu;
    unsigned u0 = *(const unsigned*)(ht8 + i0 * 128u + sub4);
    unsigned u1 = *(const unsigned*)(ht8 + i1 * 128u + sub4);
    unsigned u2 = *(const unsigned*)(ht8 + i2 * 128u + sub4);
    unsigned u3 = *(const unsigned*)(ht8 + i3 * 128u + sub4);
    float g0 = gate_<LAYER>(r0) * scales[i0];
    float g1 = gate_<LAYER>(r1) * scales[i1];
    float g2 = gate_<LAYER>(r2) * scales[i2];
    float g3 = gate_<LAYER>(r3) * scales[i3];
    sgs += g0 + g1 + g2 + g3;
    ACC4(u0, g0) ACC4(u1, g1) ACC4(u2, g2) ACC4(u3, g3)
  }
  for (; j + 2 <= c; j += 2) {   // one pair
    uint2 r = csr[s + j + p];
    unsigned i0 = r.x & 0x1ffffu;
    unsigned u = *(const unsigned*)(ht8 + i0 * 128u + sub4);
    float g = gate_<LAYER>(r) * scales[i0];
    sgs += g;
    ACC4(u, g)
  }
  if (j < c) {                   // odd leftover: half 0 only
    uint2 r = csr[s + j];
    unsigned i0 = r.x & 0x1ffffu;
    unsigned u = *(const unsigned*)(ht8 + i0 * 128u + sub4);
    float g = (p == 0) ? gate_<LAYER>(r) * scales[i0] : 0.f;
    sgs += g;
    ACC4(u, g)
  }
  // combine the two halves (lanes l and l+32 cover identical columns)
  a0 += __shfl_xor(a0, 32); a1 += __shfl_xor(a1, 32);
  a2 += __shfl_xor(a2, 32); a3 += __shfl_xor(a3, 32);
  sgs += __shfl_xor(sgs, 32);
  float corr = 128.f * sgs;
  float inv = 1.f / (float)(c + 1);
  a0 = fmaxf((a0 - corr) * inv, 0.f);
  a1 = fmaxf((a1 - corr) * inv, 0.f);
  a2 = fmaxf((a2 - corr) * inv, 0.f);
  a3 = fmaxf((a3 - corr) * inv, 0.f);
  if (p == 0) {
    __half2 h01 = __floats2half2_rn(a0, a1);
    __half2 h23 = __floats2half2_rn(a2, a3);
    uint2 outw;
    outw.x = *(unsigned*)&h01;
    outw.y = *(unsigned*)&h23;
    *(uint2*)((char*)hout + (size_t)node * 256 + (size_t)sub * 8) = outw;
  }
}

// ---------------------------------------------------------------------------
extern "C" void kernel_launch(void* const* d_in, const int* in_sizes, int n_in,
                              void* d_out, int out_size, void* d_ws, size_t ws_size,
                              hipStream_t stream) {
  int ob = (out_size + 255) / 256;

  const float *x, *ea, *l1W, *l1b, *l2W, *l2b, *t1W, *t1b, *t2W, *t2b;
  const float *convW[3], *convb[3], *edgew[3];
  const int* ei;

  if (n_in == 20) {          // tuples flattened to separate entries
    x = (const float*)d_in[0]; ei = (const int*)d_in[1]; ea = (const float*)d_in[2];
    for (int l = 0; l < 3; l++) {
      convW[l] = (const float*)d_in[3 + l];
      convb[l] = (const float*)d_in[6 + l];
      edgew[l] = (const float*)d_in[9 + l];
    }
    l1W = (const float*)d_in[12]; l1b = (const float*)d_in[13];
    l2W = (const float*)d_in[14]; l2b = (const float*)d_in[15];
    t1W = (const float*)d_in[16]; t1b = (const float*)d_in[17];
    t2W = (const float*)d_in[18]; t2b = (const float*)d_in[19];
  } else if (n_in == 14) {   // each tuple is ONE concatenated buffer
    x = (const float*)d_in[0]; ei = (const int*)d_in[1]; ea = (const float*)d_in[2];
    const float* cw = (const float*)d_in[3];
    const float* cb = (const float*)d_in[4];
    const float* ew = (const float*)d_in[5];
    for (int l = 0; l < 3; l++) {
      convW[l] = cw + (size_t)l * 128 * 128;
      convb[l] = cb + (size_t)l * 128;
      edgew[l] = ew + l;
    }
    l1W = (const float*)d_in[6];  l1b = (const float*)d_in[7];
    l2W = (const float*)d_in[8];  l2b = (const float*)d_in[9];
    t1W = (const float*)d_in[10]; t1b = (const float*)d_in[11];
    t2W = (const float*)d_in[12]; t2b = (const float*)d_in[13];
  } else {
    sentinel_kernel<<<ob, 256, 0, stream>>>((float*)d_out, out_size,
                                            900.0f + (float)n_in);
    return;
  }

  int n = in_sizes[0] / 129;   // 100000
  int E = in_sizes[2];         // 1600000

  char* ws = (char*)d_ws;
  size_t off = 0;
  auto take = [&](size_t bytes) -> void* {
    void* p = ws + off;
    off = (off + bytes + 255) & ~(size_t)255;
    return p;
  };
  size_t csr_bytes = (size_t)E * 8;
  size_t cnt_bytes = ((size_t)n + 1) * CNT_STRIDE * 4;
  int*      flag    = (int*)take(256);
  uint2*    csr     = (uint2*)take(csr_bytes > cnt_bytes ? csr_bytes : cnt_bytes);
  int*      counts  = (int*)csr;      // alias: counts dead before csr written
  int*      starts  = (int*)take(((size_t)n + 1) * 4);
  int*      bsums   = (int*)take(512 * 4);
  float*    tbuf    = (float*)take((size_t)n * 4);
  float*    x0buf   = (float*)take((size_t)n * 4);
  int*      slot    = (int*)take((size_t)E * 4);             // 6.4 MB
  _Float16* h16     = (_Float16*)take((size_t)n * 128 * 2);  // 25.6 MB
  unsigned char* ht8 = (unsigned char*)take((size_t)n * 128); // 12.8 MB
  float*    scales  = (float*)take((size_t)n * 4);           // 400 KB

  if (off > ws_size) {
    sentinel_kernel<<<ob, 256, 0, stream>>>((float*)d_out, out_size,
                                            1000.0f + (float)(ws_size >> 20));
    return;
  }

  int eb = (E + 255) / 256;
  int nb1 = (n + 1 + 255) / 256;  // scan1 covers n+1 entries; 392 <= 512
  int zb = ((n + 1) * CNT_STRIDE + 255) / 256;

  init_kernel<<<zb, 256, 0, stream>>>(ei, flag, counts, n);
  rank_kernel<<<eb, 256, 0, stream>>>(ei, E, n, flag, slot, counts);
  scan1_kernel<<<nb1, 256, 0, stream>>>(counts, n, starts, bsums);
  scan2_kernel<<<1, 512, 0, stream>>>(bsums, nb1);
  scatter_kernel<<<(eb + 3) / 4, 256, 0, stream>>>(ei, slot, starts, bsums, ea, E, n,
                                                   flag, edgew[0], edgew[1], edgew[2],
                                                   csr);

  int sb = (int)(((size_t)n * 128 + 255) / 256);
  slice_kernel<<<sb, 256, 0, stream>>>(x, h16, x0buf, n);
  // tnet: W1=t1W (129x64), h-rows 1..128, extra=x0 via row 0
  head_mfma_kernel<<<(n + 63) / 64, 256, 0, stream>>>(h16, x0buf, t1W, t1b, t2W, t2b,
                                                      tbuf, n, 1, 0);

  int gemm_grid = min((n + 63) / 64, 1024);
  gemm_mfma_kernel<<<gemm_grid, 256, 0, stream>>>(h16, convW[0], convb[0], ht8, scales, n);
  agg_kernel<0><<<(n + 3) / 4, 256, 0, stream>>>(ht8, scales, csr, starts, bsums,
                                                 edgew[0], (__half2*)h16, n);
  gemm_mfma_kernel<<<gemm_grid, 256, 0, stream>>>(h16, convW[1], convb[1], ht8, scales, n);
  agg_kernel<1><<<(n + 3) / 4, 256, 0, stream>>>(ht8, scales, csr, starts, bsums,
                                                 edgew[1], (__half2*)h16, n);
  gemm_mfma_kernel<<<gemm_grid, 256, 0, stream>>>(h16, convW[2], convb[2], ht8, scales, n);
  agg_kernel<2><<<(n + 3) / 4, 256, 0, stream>>>(ht8, scales, csr, starts, bsums,
                                                 edgew[2], (__half2*)h16, n);

  // mlp: W1=l1W (129x64), h-rows 0..127, extra=t via row 128
  head_mfma_kernel<<<(n + 63) / 64, 256, 0, stream>>>(h16, tbuf, l1W, l1b, l2W, l2b,
                                                      (float*)d_out, n, 0, 128);
}